// Round 4
// baseline (550.117 us; speedup 1.0000x reference)
//
#include <hip/hip_runtime.h>

typedef __attribute__((ext_vector_type(8))) _Float16 halfx8;
typedef __attribute__((ext_vector_type(8))) short short8;
typedef __attribute__((ext_vector_type(4))) float f32x4;

#define DI __device__ __forceinline__

DI unsigned short h2us(_Float16 h) { return __builtin_bit_cast(unsigned short, h); }

DI void gload_lds16(const void* g, void* l) {
  __builtin_amdgcn_global_load_lds(
      (const __attribute__((address_space(1))) void*)g,
      (__attribute__((address_space(3))) void*)l, 16, 0, 0);
}

// ---------------------------------------------------------------------------
// Stage 0: convert x f32 (exact fp16 values, harness-promoted) -> f16 in ws.
// ---------------------------------------------------------------------------
__global__ void __launch_bounds__(256) conv_x(const float* __restrict__ x,
                                              unsigned short* __restrict__ Xh,
                                              long total) {
  long i = ((long)blockIdx.x * 256 + threadIdx.x) * 8;
  if (i >= total) return;
  f32x4 a = *(const f32x4*)&x[i];
  f32x4 b = *(const f32x4*)&x[i + 4];
  short8 v;
#pragma unroll
  for (int j = 0; j < 4; ++j) {
    v[j] = (short)h2us((_Float16)a[j]);
    v[4 + j] = (short)h2us((_Float16)b[j]);
  }
  *(short8*)&Xh[i] = v;
}

// ---------------------------------------------------------------------------
// Stage 1: dequantize qweight [K/8][N] (8 nibbles along K) -> Wt [N][K] f16.
// w = (q - (z+1)) * s, computed as one f32 product + single RNE round to fp16
// == the reference's fp16 multiply bit-for-bit (operands are fp16-exact).
// ---------------------------------------------------------------------------
__global__ void __launch_bounds__(256) dequant_wt(
    const int* __restrict__ qweight, const int* __restrict__ qzeros,
    const float* __restrict__ scales, const int* __restrict__ g_idx,
    unsigned short* __restrict__ Wt, int N, int K) {
  int t = blockIdx.x * 256 + threadIdx.x;
  int n = t % N;
  int k0 = (t / N) * 64;
  if (k0 >= K) return;
  int g = g_idx[k0];  // uniform within the 64-k run (GS=128)
  float s = scales[(size_t)g * N + n];
  unsigned zw = (unsigned)qzeros[(size_t)g * (N >> 3) + (n >> 3)];
  int z1 = (int)((zw >> ((n & 7) * 4)) & 0xFu) + 1;
  int r0 = k0 >> 3;
#pragma unroll
  for (int i = 0; i < 8; ++i) {
    unsigned qw = (unsigned)qweight[(size_t)(r0 + i) * N + n];
    short8 v;
#pragma unroll
    for (int j = 0; j < 8; ++j) {
      int qi = (int)((qw >> (4 * j)) & 0xFu);
      v[j] = (short)h2us((_Float16)((float)(qi - z1) * s));
    }
    *(short8*)&Wt[(size_t)n * K + k0 + i * 8] = v;
  }
}

// ---------------------------------------------------------------------------
// Stage 2: f16 GEMM, m97 structure. out[M][N] = A[M][K] * Wt[N][K]^T + bias.
// 128x128 tile, BK=32, 4 waves (2x2), acc[4][4] f32x4/wave, f32 output.
// MODE0: A,B f16 from ws via global_load_lds.  MODE1: A from f32 x (reg-
// staged+convert), B f16 from ws.  MODE2: A from f32 x, B dequant in-kernel.
// ---------------------------------------------------------------------------
template <int MODE>
__global__ void __launch_bounds__(256, 2) gemm_f16(
    const unsigned short* __restrict__ Xh,  // f16 A  (MODE0)
    const float* __restrict__ Xf,           // f32 A  (MODE1/2)
    const unsigned short* __restrict__ Wt,  // f16 B  (MODE0/1)
    const int* __restrict__ qweight, const int* __restrict__ qzeros,
    const float* __restrict__ scales, const int* __restrict__ g_idx,
    const float* __restrict__ bias, float* __restrict__ out,
    int M, int N, int K) {
  constexpr int BM = 128, BN = 128, BK = 32;
  __shared__ unsigned short Als[BM * BK];  // [row m][k] linear
  __shared__ unsigned short Bls[BN * BK];  // [row n][k] linear

  const int tid = threadIdx.x;
  const int lane = tid & 63;
  const int wave = tid >> 6;
  const int wr = wave >> 1, wc = wave & 1;  // 2x2 waves, each 64x64 out
  const int nbm = M / BM;
  const int bm = blockIdx.x % nbm, bn = blockIdx.x / nbm;
  const int m0 = bm * BM, n0 = bn * BN;

  f32x4 acc[4][4] = {};

  const int lr = lane & 15;        // fragment row/col within 16
  const int ko = (lane >> 4) * 8;  // k sub-offset for fragments

  for (int kk = 0; kk < K; kk += BK) {
    short8 av[2], bv[2];
    if constexpr (MODE != 0) {
      // reg-stage A from f32 x, convert to f16 (issued pre-barrier: no LDS)
#pragma unroll
      for (int i = 0; i < 2; ++i) {
        int e = i * 256 + tid;
        int row = e >> 2, uo = e & 3;
        const float* p = &Xf[(size_t)(m0 + row) * K + kk + uo * 8];
        f32x4 a = *(const f32x4*)p;
        f32x4 b = *(const f32x4*)(p + 4);
        short8 v;
#pragma unroll
        for (int j = 0; j < 4; ++j) {
          v[j] = (short)h2us((_Float16)a[j]);
          v[4 + j] = (short)h2us((_Float16)b[j]);
        }
        av[i] = v;
      }
    }
    if constexpr (MODE == 2) {
      // dequant B tile into regs: word w -> n=n0+(w>>2), k-octet r=(w&3)
      int g = g_idx[kk];
      int r0k = kk >> 3;
#pragma unroll
      for (int i = 0; i < 2; ++i) {
        int w = i * 256 + tid;
        int n = n0 + (w >> 2);
        int r = r0k + (w & 3);
        unsigned qw = (unsigned)qweight[(size_t)r * N + n];
        float s = scales[(size_t)g * N + n];
        unsigned zw = (unsigned)qzeros[(size_t)g * (N >> 3) + (n >> 3)];
        int z1 = (int)((zw >> ((n & 7) * 4)) & 0xFu) + 1;
        short8 v;
#pragma unroll
        for (int j = 0; j < 8; ++j) {
          int qi = (int)((qw >> (4 * j)) & 0xFu);
          v[j] = (short)h2us((_Float16)((float)(qi - z1) * s));
        }
        bv[i] = v;
      }
    }

    __syncthreads();  // previous tile fully consumed by all waves

    if constexpr (MODE == 0) {
#pragma unroll
      for (int i = 0; i < 2; ++i) {
        int e = i * 256 + tid;
        int row = e >> 2, uo = e & 3;
        gload_lds16(Xh + (size_t)(m0 + row) * K + kk + uo * 8, &Als[e * 8]);
        gload_lds16(Wt + (size_t)(n0 + row) * K + kk + uo * 8, &Bls[e * 8]);
      }
    } else {
      if constexpr (MODE == 1) {
#pragma unroll
        for (int i = 0; i < 2; ++i) {
          int e = i * 256 + tid;
          int row = e >> 2, uo = e & 3;
          gload_lds16(Wt + (size_t)(n0 + row) * K + kk + uo * 8, &Bls[e * 8]);
        }
      }
#pragma unroll
      for (int i = 0; i < 2; ++i) {
        int e = i * 256 + tid;
        *(short8*)&Als[e * 8] = av[i];
        if constexpr (MODE == 2) *(short8*)&Bls[e * 8] = bv[i];
      }
    }
    __syncthreads();  // staging visible (vmcnt/lgkm drained at barrier)

    halfx8 af[4], bfr[4];
#pragma unroll
    for (int mi = 0; mi < 4; ++mi)
      af[mi] = __builtin_bit_cast(
          halfx8, *(const short8*)&Als[(wr * 64 + mi * 16 + lr) * BK + ko]);
#pragma unroll
    for (int nj = 0; nj < 4; ++nj)
      bfr[nj] = __builtin_bit_cast(
          halfx8, *(const short8*)&Bls[(wc * 64 + nj * 16 + lr) * BK + ko]);
#pragma unroll
    for (int mi = 0; mi < 4; ++mi)
#pragma unroll
      for (int nj = 0; nj < 4; ++nj)
        acc[mi][nj] = __builtin_amdgcn_mfma_f32_16x16x32_f16(
            af[mi], bfr[nj], acc[mi][nj], 0, 0, 0);
  }

  // ---- epilogue: C/D layout col=lane&15, row=(lane>>4)*4+j; f32 output ----
#pragma unroll
  for (int nj = 0; nj < 4; ++nj) {
    int col = n0 + wc * 64 + nj * 16 + lr;
    float bv2 = bias[col];
#pragma unroll
    for (int mi = 0; mi < 4; ++mi) {
      int row0 = m0 + wr * 64 + mi * 16 + ((lane >> 4) << 2);
#pragma unroll
      for (int j = 0; j < 4; ++j)
        out[(size_t)(row0 + j) * N + col] = acc[mi][nj][j] + bv2;
    }
  }
}

extern "C" void kernel_launch(void* const* d_in, const int* in_sizes, int n_in,
                              void* d_out, int out_size, void* d_ws,
                              size_t ws_size, hipStream_t stream) {
  const float* x = (const float*)d_in[0];        // f32 (fp16-promoted) [B,S,K]
  const int* qweight = (const int*)d_in[1];      // [K/8, N]
  const int* qzeros = (const int*)d_in[2];       // [G, N/8]
  const float* scales = (const float*)d_in[3];   // f32 (fp16-promoted) [G, N]
  const int* g_idx = (const int*)d_in[4];        // [K]
  const float* bias = (const float*)d_in[5];     // f32 (fp16-promoted) [N]
  float* out = (float*)d_out;                    // f32 [B,S,N]

  const int K = in_sizes[4];
  const int N = in_sizes[5];
  const int M = in_sizes[0] / K;  // B*S = 8192

  dim3 blk(256);
  dim3 grid((M / 128) * (N / 128));
  const size_t xh_bytes = (size_t)M * K * 2;
  const size_t wt_bytes = (size_t)N * K * 2;
  const long xtotal = (long)M * K;
  const int wt_blocks = (K / 64) * N / 256;

  if (ws_size >= xh_bytes + wt_bytes) {
    unsigned short* Xh = (unsigned short*)d_ws;
    unsigned short* Wt = (unsigned short*)((char*)d_ws + xh_bytes);
    conv_x<<<dim3((int)(xtotal / 2048)), blk, 0, stream>>>(x, Xh, xtotal);
    dequant_wt<<<dim3(wt_blocks), blk, 0, stream>>>(qweight, qzeros, scales,
                                                    g_idx, Wt, N, K);
    gemm_f16<0><<<grid, blk, 0, stream>>>(Xh, nullptr, Wt, qweight, qzeros,
                                          scales, g_idx, bias, out, M, N, K);
  } else if (ws_size >= wt_bytes) {
    unsigned short* Wt = (unsigned short*)d_ws;
    dequant_wt<<<dim3(wt_blocks), blk, 0, stream>>>(qweight, qzeros, scales,
                                                    g_idx, Wt, N, K);
    gemm_f16<1><<<grid, blk, 0, stream>>>(nullptr, x, Wt, qweight, qzeros,
                                          scales, g_idx, bias, out, M, N, K);
  } else {
    gemm_f16<2><<<grid, blk, 0, stream>>>(nullptr, x, nullptr, qweight, qzeros,
                                          scales, g_idx, bias, out, M, N, K);
  }
}

// Round 5
// 503.426 us; speedup vs baseline: 1.0927x; 1.0927x over previous
//
#include <hip/hip_runtime.h>

typedef __attribute__((ext_vector_type(8))) _Float16 halfx8;
typedef __attribute__((ext_vector_type(8))) short short8;
typedef __attribute__((ext_vector_type(4))) float f32x4;

#define DI __device__ __forceinline__

DI unsigned short h2us(_Float16 h) { return __builtin_bit_cast(unsigned short, h); }

DI void gload_lds16(const void* g, void* l) {
  __builtin_amdgcn_global_load_lds(
      (const __attribute__((address_space(1))) void*)g,
      (__attribute__((address_space(3))) void*)l, 16, 0, 0);
}

// ---------------------------------------------------------------------------
// Stage 0: convert x f32 (exact fp16 values, harness-promoted) -> f16 in ws.
// ---------------------------------------------------------------------------
__global__ void __launch_bounds__(256) conv_x(const float* __restrict__ x,
                                              unsigned short* __restrict__ Xh,
                                              long total) {
  long i = ((long)blockIdx.x * 256 + threadIdx.x) * 8;
  if (i >= total) return;
  f32x4 a = *(const f32x4*)&x[i];
  f32x4 b = *(const f32x4*)&x[i + 4];
  short8 v;
#pragma unroll
  for (int j = 0; j < 4; ++j) {
    v[j] = (short)h2us((_Float16)a[j]);
    v[4 + j] = (short)h2us((_Float16)b[j]);
  }
  *(short8*)&Xh[i] = v;
}

// ---------------------------------------------------------------------------
// Stage 1: dequant qweight [K/8][N] (8 nibbles along K) -> Wt [N][K] f16.
// v2: thread -> (k-octet, n) so each 8-lane group writes one contiguous
// 128 B run of a Wt row (8 runs/wave vs 64 scattered 16 B stores in v1).
// w = (q - (z+1)) * s with single RNE round to fp16 == reference bit-exact.
// ---------------------------------------------------------------------------
__global__ void __launch_bounds__(256) dequant_wt(
    const int* __restrict__ qweight, const int* __restrict__ qzeros,
    const float* __restrict__ scales, const int* __restrict__ g_idx,
    unsigned short* __restrict__ Wt, int N, int K) {
  int T = blockIdx.x * 256 + threadIdx.x;
  int oct = T & 7;        // which 8-k octet within a 64-k run
  int rest = T >> 3;
  int n = rest % N;
  int kblk = rest / N;
  int k = kblk * 64 + oct * 8;
  if (k >= K) return;
  int g = g_idx[k];  // uniform across the octet (GS=128, k%8==0)
  float s = scales[(size_t)g * N + n];
  unsigned zw = (unsigned)qzeros[(size_t)g * (N >> 3) + (n >> 3)];
  int z1 = (int)((zw >> ((n & 7) * 4)) & 0xFu) + 1;
  unsigned qw = (unsigned)qweight[(size_t)(kblk * 8 + oct) * N + n];
  short8 v;
#pragma unroll
  for (int j = 0; j < 8; ++j) {
    int qi = (int)((qw >> (4 * j)) & 0xFu);
    v[j] = (short)h2us((_Float16)((float)(qi - z1) * s));
  }
  *(short8*)&Wt[(size_t)n * K + k] = v;
}

// ---------------------------------------------------------------------------
// Stage 2: f16 GEMM, 256x256 tile, BK=32, 8 waves (2M x 4N), 4-buffer LDS
// (128 KiB dynamic), counted vmcnt + raw s_barrier, XOR-swizzled LDS.
//
// LDS layout per tile buffer: [256 rows][4 slots of 16B]; linear dest for
// global_load_lds; slot holds global k-chunk (slot ^ ((row>>1)&3))  — the
// inverse-swizzled-source pattern (rule #21). Fragment ds_read_b128 groups
// of 8 consecutive lanes then hit 8 distinct bank-quads (conflict-free).
//
// Buffer rotation: iter t reads buf t&3, stages tile t+3 into buf (t+3)&3
// = (t-1)&3 (last read iter t-1; protected by iter t-1's lgkm(0)+barrier).
// vmcnt ledger: prologue stages tiles 0,1,2 (12 loads/thread) -> vmcnt(8)
// leaves tiles 1,2 in flight, tile 0 landed. Steady: vmcnt(8) = tile t+1
// landed (t+2,t+3 in flight). Tail: vmcnt(4) at t==NT-3, vmcnt(0) after.
// ---------------------------------------------------------------------------
__global__ void __launch_bounds__(512, 2) gemm256(
    const unsigned short* __restrict__ Xh,  // f16 A [M][K]
    const unsigned short* __restrict__ Wt,  // f16 B [N][K]
    const float* __restrict__ bias, float* __restrict__ out,
    int M, int N, int K) {
  extern __shared__ unsigned short smem[];      // 4*8192 A + 4*8192 B elems
  unsigned short* As = smem;
  unsigned short* Bs = smem + 4 * 8192;

  const int tid = threadIdx.x;
  const int lane = tid & 63;
  const int wave = tid >> 6;
  const int wm = wave >> 2, wn = wave & 3;      // 2x4 waves; 128x64 out each

  // XCD-bijective blockIdx swizzle (gridDim % 8 == 0 here: 512)
  const int cpx = gridDim.x >> 3;
  const int wg = ((int)blockIdx.x & 7) * cpx + ((int)blockIdx.x >> 3);
  const int nbm = M >> 8;
  const int bm = wg % nbm, bn = wg / nbm;
  const int m0 = bm << 8, n0 = bn << 8;

  const int NT = K >> 5;  // K/32 tiles

  // staging addressing: 16B-unit index L = i*512+tid; row=L>>2, slot=L&3;
  // LDS dest byte = L*16 (linear); global chunk = slot ^ ((row>>1)&3).
  const int L0 = tid, L1 = 512 + tid;
  const int r0s = L0 >> 2, c0 = (L0 & 3) ^ ((r0s >> 1) & 3);
  const int r1s = L1 >> 2, c1 = (L1 & 3) ^ ((r1s >> 1) & 3);
  const size_t aoff0 = (size_t)(m0 + r0s) * K + c0 * 8;
  const size_t aoff1 = (size_t)(m0 + r1s) * K + c1 * 8;
  const size_t boff0 = (size_t)(n0 + r0s) * K + c0 * 8;
  const size_t boff1 = (size_t)(n0 + r1s) * K + c1 * 8;

#define STAGE(t)                                               \
  {                                                            \
    int b_ = (t) & 3;                                          \
    int kk_ = (t) << 5;                                        \
    gload_lds16(Xh + aoff0 + kk_, &As[b_ * 8192 + L0 * 8]);    \
    gload_lds16(Xh + aoff1 + kk_, &As[b_ * 8192 + L1 * 8]);    \
    gload_lds16(Wt + boff0 + kk_, &Bs[b_ * 8192 + L0 * 8]);    \
    gload_lds16(Wt + boff1 + kk_, &Bs[b_ * 8192 + L1 * 8]);    \
  }

  STAGE(0); STAGE(1); STAGE(2);
  asm volatile("s_waitcnt vmcnt(8)" ::: "memory");  // tile 0 landed
  __builtin_amdgcn_s_barrier();
  __builtin_amdgcn_sched_barrier(0);

  f32x4 acc[8][4] = {};
  const int lr = lane & 15;
  // swizzled element offset within a row: chunk = lane>>4, sel = (lr>>1)&3
  const int xch = (((lane >> 4) ^ ((lane >> 1) & 3)) * 8);
  const int arow = wm * 128 + lr;  // + mi*16
  const int brow = wn * 64 + lr;   // + nj*16

  for (int t = 0; t < NT; ++t) {
    if (t + 3 < NT) STAGE(t + 3);

    const unsigned short* Ab = &As[(t & 3) * 8192];
    const unsigned short* Bb = &Bs[(t & 3) * 8192];
    halfx8 af[8], bf[4];
#pragma unroll
    for (int mi = 0; mi < 8; ++mi)
      af[mi] = __builtin_bit_cast(
          halfx8, *(const short8*)&Ab[(arow + mi * 16) * 32 + xch]);
#pragma unroll
    for (int nj = 0; nj < 4; ++nj)
      bf[nj] = __builtin_bit_cast(
          halfx8, *(const short8*)&Bb[(brow + nj * 16) * 32 + xch]);

    __builtin_amdgcn_s_setprio(1);
#pragma unroll
    for (int mi = 0; mi < 8; ++mi)
#pragma unroll
      for (int nj = 0; nj < 4; ++nj)
        acc[mi][nj] = __builtin_amdgcn_mfma_f32_16x16x32_f16(
            af[mi], bf[nj], acc[mi][nj], 0, 0, 0);
    __builtin_amdgcn_s_setprio(0);

    if (t < NT - 3)
      asm volatile("s_waitcnt vmcnt(8)" ::: "memory");   // tile t+1 landed
    else if (t == NT - 3)
      asm volatile("s_waitcnt vmcnt(4)" ::: "memory");
    else
      asm volatile("s_waitcnt vmcnt(0)" ::: "memory");
    asm volatile("s_waitcnt lgkmcnt(0)" ::: "memory");   // my ds_reads done
    __builtin_amdgcn_sched_barrier(0);
    __builtin_amdgcn_s_barrier();                        // raw: no vmcnt drain
    __builtin_amdgcn_sched_barrier(0);
  }
#undef STAGE

  // epilogue: C/D layout col=lane&15, row=(lane>>4)*4+j; f32 out + bias
#pragma unroll
  for (int nj = 0; nj < 4; ++nj) {
    int col = n0 + wn * 64 + nj * 16 + lr;
    float bv = bias[col];
#pragma unroll
    for (int mi = 0; mi < 8; ++mi) {
      int row0 = m0 + wm * 128 + mi * 16 + ((lane >> 4) << 2);
#pragma unroll
      for (int j = 0; j < 4; ++j)
        out[(size_t)(row0 + j) * N + col] = acc[mi][nj][j] + bv;
    }
  }
}

extern "C" void kernel_launch(void* const* d_in, const int* in_sizes, int n_in,
                              void* d_out, int out_size, void* d_ws,
                              size_t ws_size, hipStream_t stream) {
  const float* x = (const float*)d_in[0];        // f32 (fp16-promoted) [B,S,K]
  const int* qweight = (const int*)d_in[1];      // [K/8, N]
  const int* qzeros = (const int*)d_in[2];       // [G, N/8]
  const float* scales = (const float*)d_in[3];   // f32 (fp16-promoted) [G, N]
  const int* g_idx = (const int*)d_in[4];        // [K]
  const float* bias = (const float*)d_in[5];     // f32 (fp16-promoted) [N]
  float* out = (float*)d_out;                    // f32 [B,S,N]

  const int K = in_sizes[4];
  const int N = in_sizes[5];
  const int M = in_sizes[0] / K;  // B*S = 8192

  unsigned short* Xh = (unsigned short*)d_ws;                   // M*K f16
  unsigned short* Wtp = (unsigned short*)((char*)d_ws + (size_t)M * K * 2);

  const long xtotal = (long)M * K;
  conv_x<<<dim3((int)(xtotal / 2048)), dim3(256), 0, stream>>>(x, Xh, xtotal);

  const int dq_blocks = (int)(((size_t)N * (K / 8)) / 256);
  dequant_wt<<<dim3(dq_blocks), dim3(256), 0, stream>>>(qweight, qzeros,
                                                        scales, g_idx, Wtp, N, K);

  const int grid = (M / 256) * (N / 256);  // 512
  hipFuncSetAttribute((const void*)gemm256,
                      hipFuncAttributeMaxDynamicSharedMemorySize, 131072);
  gemm256<<<dim3(grid), dim3(512), 131072, stream>>>(Xh, Wtp, bias, out,
                                                     M, N, K);
}

// Round 8
// 488.815 us; speedup vs baseline: 1.1254x; 1.0299x over previous
//
#include <hip/hip_runtime.h>

typedef __attribute__((ext_vector_type(8))) _Float16 halfx8;
typedef __attribute__((ext_vector_type(8))) short short8;
typedef __attribute__((ext_vector_type(4))) float f32x4;

#define DI __device__ __forceinline__

DI unsigned short h2us(_Float16 h) { return __builtin_bit_cast(unsigned short, h); }

DI void gload_lds16(const void* g, void* l) {
  __builtin_amdgcn_global_load_lds(
      (const __attribute__((address_space(1))) void*)g,
      (__attribute__((address_space(3))) void*)l, 16, 0, 0);
}

// ---------------------------------------------------------------------------
// Stage 0: convert x f32 (exact fp16 values, harness-promoted) -> f16 in ws.
// ---------------------------------------------------------------------------
__global__ void __launch_bounds__(256) conv_x(const float* __restrict__ x,
                                              unsigned short* __restrict__ Xh,
                                              long total) {
  long i = ((long)blockIdx.x * 256 + threadIdx.x) * 8;
  if (i >= total) return;
  f32x4 a = *(const f32x4*)&x[i];
  f32x4 b = *(const f32x4*)&x[i + 4];
  short8 v;
#pragma unroll
  for (int j = 0; j < 4; ++j) {
    v[j] = (short)h2us((_Float16)a[j]);
    v[4 + j] = (short)h2us((_Float16)b[j]);
  }
  *(short8*)&Xh[i] = v;
}

// ---------------------------------------------------------------------------
// Stage 1: dequant qweight [K/8][N] (8 nibbles along K) -> Wt [N][K] f16.
// thread -> (k-octet, n): each 8-lane group writes one contiguous 128 B run.
// w = (q - (z+1)) * s, single RNE round to fp16 == reference bit-exact.
// ---------------------------------------------------------------------------
__global__ void __launch_bounds__(256) dequant_wt(
    const int* __restrict__ qweight, const int* __restrict__ qzeros,
    const float* __restrict__ scales, const int* __restrict__ g_idx,
    unsigned short* __restrict__ Wt, int N, int K) {
  int T = blockIdx.x * 256 + threadIdx.x;
  int oct = T & 7;
  int rest = T >> 3;
  int n = rest % N;
  int kblk = rest / N;
  int k = kblk * 64 + oct * 8;
  if (k >= K) return;
  int g = g_idx[k];
  float s = scales[(size_t)g * N + n];
  unsigned zw = (unsigned)qzeros[(size_t)g * (N >> 3) + (n >> 3)];
  int z1 = (int)((zw >> ((n & 7) * 4)) & 0xFu) + 1;
  unsigned qw = (unsigned)qweight[(size_t)(kblk * 8 + oct) * N + n];
  short8 v;
#pragma unroll
  for (int j = 0; j < 8; ++j) {
    int qi = (int)((qw >> (4 * j)) & 0xFu);
    v[j] = (short)h2us((_Float16)((float)(qi - z1) * s));
  }
  *(short8*)&Wt[(size_t)n * K + k] = v;
}

// ---------------------------------------------------------------------------
// Stage 2: f16 GEMM, 256x256 tile, 8-phase schedule (m201 port).
// K-tile BK=64; slot = kt&1 (2 x 64 KiB LDS); 4 quadrant-phases per K-tile:
//   P0: ds_read af[mi0-3][2k] + bf[nj0-1][2k]          ; MFMA Q00 (16)
//   P1: ds_read bf[nj2-3][2k]                           ; MFMA Q01 (16)
//   P2: ds_read af[mi4-7][2k]; STAGE B(kt+2)            ; MFMA Q10 (16)
//   P3: STAGE A(kt+2); MFMA Q11 (16); vmcnt(8); barrier
// Each phase: [reads/stages] barrier; lgkmcnt(0); setprio(1); MFMA;
// setprio(0); barrier.  Region safety: B(kt+2) staged only after P1's
// closing barrier (all waves' bf reads of kt done); A(kt+2) after P2's
// (af reads done); kt+1 lives in the other slot.  vmcnt ledger (4-load
// batches B(t),A(t),B(t+1),A(t+1)): vmcnt(8) at P3 drains exactly
// B(kt+1),A(kt+1).  Prologue: stage tiles 0,1; vmcnt(8) = tile 0 landed.
// LDS swizzle: row = 128 B = 8 chunks of 16 B; slot s holds global chunk
// s^(row&7); staged via inverse-swizzled global source (linear gload_lds
// dest, rule #21); fragment reads land <=2-way bank aliasing (free).
// ---------------------------------------------------------------------------
__global__ void __launch_bounds__(512, 2) gemm8p(
    const unsigned short* __restrict__ Xh,  // f16 A [M][K]
    const unsigned short* __restrict__ Wt,  // f16 B [N][K]
    const float* __restrict__ bias, float* __restrict__ out,
    int M, int N, int K) {
  extern __shared__ unsigned short lds[];  // 2 slots x (A 16K + B 16K elems)
  const int tid = threadIdx.x;
  const int lane = tid & 63;
  const int wave = tid >> 6;
  const int wm = wave >> 2, wn = wave & 3;  // 2x4 waves; 128x64 out each

  const int cpx = gridDim.x >> 3;  // XCD-bijective swizzle (grid % 8 == 0)
  const int wg = ((int)blockIdx.x & 7) * cpx + ((int)blockIdx.x >> 3);
  const int nbm = M >> 8;
  const int bm = wg % nbm, bn = wg / nbm;
  const int m0 = bm << 8, n0 = bn << 8;

  const int KT = K >> 6;  // K/64 tiles

  // staging: unit L in [0,1024) per half-tile; thread -> L0=tid, L1=tid+512
  // row(L)=L>>3 (L1: +64, same chunk), slot=L&7, global chunk=slot^(row&7)
  const int srow = tid >> 3;
  const int scol = ((tid & 7) ^ (srow & 7)) * 8;

#define STG(P, R0, LB, kt)                                                   \
  {                                                                          \
    gload_lds16((P) + (size_t)((R0) + srow) * K + (kt) * 64 + scol,          \
                &lds[(LB) + tid * 8]);                                       \
    gload_lds16((P) + (size_t)((R0) + srow + 64) * K + (kt) * 64 + scol,     \
                &lds[(LB) + (tid + 512) * 8]);                               \
  }
#define STG_KB(kt)                                                 \
  {                                                                \
    STG(Wt, n0, (((kt)&1) * 32768) + 16384, kt);                   \
    STG(Wt, n0 + 128, (((kt)&1) * 32768) + 16384 + 8192, kt);      \
  }
#define STG_KA(kt)                                         \
  {                                                        \
    STG(Xh, m0, (((kt)&1) * 32768), kt);                   \
    STG(Xh, m0 + 128, (((kt)&1) * 32768) + 8192, kt);      \
  }

  STG_KB(0); STG_KA(0); STG_KB(1); STG_KA(1);
  asm volatile("s_waitcnt vmcnt(8)" ::: "memory");  // tile 0 landed
  __builtin_amdgcn_s_barrier();
  __builtin_amdgcn_sched_barrier(0);

  f32x4 acc[8][4] = {};
  const int lr = lane & 15, lg = lane >> 4;
  const int sx0 = (lg ^ (lr & 7)) * 8;        // ksel0: chunk=lg
  const int sx1 = ((4 + lg) ^ (lr & 7)) * 8;  // ksel1: chunk=4+lg
  const int aB = wm * 8192 + lr * 64;
  const int bB = 16384 + (wn >> 1) * 8192 + ((wn & 1) * 64 + lr) * 64;

#define RD(ofs) __builtin_bit_cast(halfx8, *(const short8*)&lds[ofs])
#define LG0                                              \
  {                                                      \
    asm volatile("s_waitcnt lgkmcnt(0)" ::: "memory");   \
    __builtin_amdgcn_sched_barrier(0);                   \
  }
#define BAR __builtin_amdgcn_s_barrier()

  for (int kt = 0; kt < KT; ++kt) {
    const int sE = (kt & 1) * 32768;
    const bool pf = (kt + 2 < KT);
    halfx8 af[4][2], bf[4][2];

    // ---- P0: af(mi0-3) + bf(nj0-1); MFMA Q00 ----
#pragma unroll
    for (int mi = 0; mi < 4; ++mi) {
      af[mi][0] = RD(sE + aB + mi * 1024 + sx0);
      af[mi][1] = RD(sE + aB + mi * 1024 + sx1);
    }
#pragma unroll
    for (int nj = 0; nj < 2; ++nj) {
      bf[nj][0] = RD(sE + bB + nj * 1024 + sx0);
      bf[nj][1] = RD(sE + bB + nj * 1024 + sx1);
    }
    BAR; LG0;
    __builtin_amdgcn_s_setprio(1);
#pragma unroll
    for (int mi = 0; mi < 4; ++mi)
#pragma unroll
      for (int nj = 0; nj < 2; ++nj)
#pragma unroll
        for (int ks = 0; ks < 2; ++ks)
          acc[mi][nj] = __builtin_amdgcn_mfma_f32_16x16x32_f16(
              af[mi][ks], bf[nj][ks], acc[mi][nj], 0, 0, 0);
    __builtin_amdgcn_s_setprio(0);
    BAR;

    // ---- P1: bf(nj2-3); MFMA Q01 ----
#pragma unroll
    for (int nj = 2; nj < 4; ++nj) {
      bf[nj][0] = RD(sE + bB + nj * 1024 + sx0);
      bf[nj][1] = RD(sE + bB + nj * 1024 + sx1);
    }
    BAR; LG0;
    __builtin_amdgcn_s_setprio(1);
#pragma unroll
    for (int mi = 0; mi < 4; ++mi)
#pragma unroll
      for (int nj = 2; nj < 4; ++nj)
#pragma unroll
        for (int ks = 0; ks < 2; ++ks)
          acc[mi][nj] = __builtin_amdgcn_mfma_f32_16x16x32_f16(
              af[mi][ks], bf[nj][ks], acc[mi][nj], 0, 0, 0);
    __builtin_amdgcn_s_setprio(0);
    BAR;
    __builtin_amdgcn_sched_barrier(0);  // pin: STG_KB stays after this bar

    // ---- P2: af(mi4-7); stage B(kt+2); MFMA Q10 ----
#pragma unroll
    for (int mi = 0; mi < 4; ++mi) {
      af[mi][0] = RD(sE + aB + (mi + 4) * 1024 + sx0);
      af[mi][1] = RD(sE + aB + (mi + 4) * 1024 + sx1);
    }
    if (pf) STG_KB(kt + 2);
    BAR; LG0;
    __builtin_amdgcn_s_setprio(1);
#pragma unroll
    for (int mi = 0; mi < 4; ++mi)
#pragma unroll
      for (int nj = 0; nj < 2; ++nj)
#pragma unroll
        for (int ks = 0; ks < 2; ++ks)
          acc[4 + mi][nj] = __builtin_amdgcn_mfma_f32_16x16x32_f16(
              af[mi][ks], bf[nj][ks], acc[4 + mi][nj], 0, 0, 0);
    __builtin_amdgcn_s_setprio(0);
    BAR;
    __builtin_amdgcn_sched_barrier(0);  // pin: STG_KA stays after this bar

    // ---- P3: stage A(kt+2); MFMA Q11; vmcnt; barrier ----
    if (pf) STG_KA(kt + 2);
    BAR;
    __builtin_amdgcn_s_setprio(1);
#pragma unroll
    for (int mi = 0; mi < 4; ++mi)
#pragma unroll
      for (int nj = 2; nj < 4; ++nj)
#pragma unroll
        for (int ks = 0; ks < 2; ++ks)
          acc[4 + mi][nj] = __builtin_amdgcn_mfma_f32_16x16x32_f16(
              af[mi][ks], bf[nj][ks], acc[4 + mi][nj], 0, 0, 0);
    __builtin_amdgcn_s_setprio(0);
    if (pf)
      asm volatile("s_waitcnt vmcnt(8)" ::: "memory");  // tile kt+1 landed
    else
      asm volatile("s_waitcnt vmcnt(0)" ::: "memory");  // drain tail
    BAR;
    __builtin_amdgcn_sched_barrier(0);  // pin: next window's reads stay after
  }
#undef STG
#undef STG_KA
#undef STG_KB
#undef RD
#undef LG0
#undef BAR

  // epilogue: C/D layout col=lane&15, row=(lane>>4)*4+j; f32 out + bias
#pragma unroll
  for (int nj = 0; nj < 4; ++nj) {
    int col = n0 + wn * 64 + nj * 16 + lr;
    float bv = bias[col];
#pragma unroll
    for (int mi = 0; mi < 8; ++mi) {
      int row0 = m0 + wm * 128 + mi * 16 + (lg << 2);
#pragma unroll
      for (int j = 0; j < 4; ++j)
        out[(size_t)(row0 + j) * N + col] = acc[mi][nj][j] + bv;
    }
  }
}

extern "C" void kernel_launch(void* const* d_in, const int* in_sizes, int n_in,
                              void* d_out, int out_size, void* d_ws,
                              size_t ws_size, hipStream_t stream) {
  const float* x = (const float*)d_in[0];        // f32 (fp16-promoted) [B,S,K]
  const int* qweight = (const int*)d_in[1];      // [K/8, N]
  const int* qzeros = (const int*)d_in[2];       // [G, N/8]
  const float* scales = (const float*)d_in[3];   // f32 (fp16-promoted) [G, N]
  const int* g_idx = (const int*)d_in[4];        // [K]
  const float* bias = (const float*)d_in[5];     // f32 (fp16-promoted) [N]
  float* out = (float*)d_out;                    // f32 [B,S,N]

  const int K = in_sizes[4];
  const int N = in_sizes[5];
  const int M = in_sizes[0] / K;  // B*S = 8192

  unsigned short* Xh = (unsigned short*)d_ws;                   // M*K f16
  unsigned short* Wtp = (unsigned short*)((char*)d_ws + (size_t)M * K * 2);

  const long xtotal = (long)M * K;
  conv_x<<<dim3((int)(xtotal / 2048)), dim3(256), 0, stream>>>(x, Xh, xtotal);

  const int dq_blocks = (int)(((size_t)N * (K / 8)) / 256);
  dequant_wt<<<dim3(dq_blocks), dim3(256), 0, stream>>>(qweight, qzeros,
                                                        scales, g_idx, Wtp, N, K);

  const int grid = (M / 256) * (N / 256);  // 512, % 8 == 0
  hipFuncSetAttribute((const void*)gemm8p,
                      hipFuncAttributeMaxDynamicSharedMemorySize, 131072);
  gemm8p<<<dim3(grid), dim3(512), 131072, stream>>>(Xh, Wtp, bias, out,
                                                    M, N, K);
}